// Round 7
// baseline (328.426 us; speedup 1.0000x reference)
//
#include <hip/hip_runtime.h>

// Problem constants
#define B_    16
#define N1_   32
#define NL_   256
#define DM_   16
#define A_    2
#define DK_   8
#define DV_   8
#define DOUT_ 16

#define NBN   (B_ * N1_)                  // 512 blocks
#define PROJ_ELEMS (NBN * NL_ * DOUT_)    // 2097152

// LDS layout (float offsets). QP padded to stride 17 (conflict-free strided reads).
#define QP_OFF   0                        // 256*17 = 4352
#define KP_OFF   4352                     // 256*16 = 4096 (16B-aligned)
#define VP_OFF   8448                     // 4096
#define WQ_OFF   12544                    // 256
#define WK_OFF   12800                    // 256
#define WV_OFF   13056                    // 256
#define WO_OFF   13312                    // 256
#define LDS_FLOATS 13568                  // 54272 B
// Epilogue aliases (QP/KP/VP dead by then; weights region untouched):
#define EMBA_OFF 0
#define EMBB_OFF 4352

__global__ __launch_bounds__(256, 2)
void mha_relu_kernel(const float* __restrict__ Q,
                     const float* __restrict__ K,
                     const float* __restrict__ V,
                     const float* __restrict__ Wq,
                     const float* __restrict__ Wk,
                     const float* __restrict__ Wv,
                     const float* __restrict__ Wo,
                     float* __restrict__ proj_out,
                     float* __restrict__ attn_out)
{
    __shared__ float lds[LDS_FLOATS];

    const int tid = threadIdx.x;
    const int bn  = blockIdx.x;
    const int w   = tid >> 6;             // wave id 0..3 -> z-range [64w, 64w+64)
    const int l   = tid & 63;             // lane

    // ---- weights -> LDS ----
    lds[WQ_OFF + tid] = Wq[tid];
    lds[WK_OFF + tid] = Wk[tid];
    lds[WV_OFF + tid] = Wv[tid];
    lds[WO_OFF + tid] = Wo[tid];
    __syncthreads();

    const size_t inoff = (size_t)bn * NL_ * DM_;

    // ---- phase 1: per-row projections (thread t computes row t) ----
    {
        float rowbuf[16], acc[16];

        // Q row -> QP (padded stride 17; stays live through both pair-phases)
        {
            const float4* p = (const float4*)(Q + inoff + (size_t)tid * DM_);
            #pragma unroll
            for (int i = 0; i < 4; ++i) {
                float4 t = p[i];
                rowbuf[4*i+0] = t.x; rowbuf[4*i+1] = t.y;
                rowbuf[4*i+2] = t.z; rowbuf[4*i+3] = t.w;
            }
            #pragma unroll
            for (int c = 0; c < 16; ++c) acc[c] = 0.f;
            #pragma unroll
            for (int i = 0; i < 16; ++i) {
                const float qi = rowbuf[i];
                #pragma unroll
                for (int c = 0; c < 16; ++c) acc[c] += qi * lds[WQ_OFF + i*16 + c];
            }
            #pragma unroll
            for (int c = 0; c < 16; ++c) lds[QP_OFF + tid*17 + c] = acc[c];
        }
        // K row -> KP (stride 16)
        {
            const float4* p = (const float4*)(K + inoff + (size_t)tid * DM_);
            #pragma unroll
            for (int i = 0; i < 4; ++i) {
                float4 t = p[i];
                rowbuf[4*i+0] = t.x; rowbuf[4*i+1] = t.y;
                rowbuf[4*i+2] = t.z; rowbuf[4*i+3] = t.w;
            }
            #pragma unroll
            for (int c = 0; c < 16; ++c) acc[c] = 0.f;
            #pragma unroll
            for (int i = 0; i < 16; ++i) {
                const float ki = rowbuf[i];
                #pragma unroll
                for (int c = 0; c < 16; ++c) acc[c] += ki * lds[WK_OFF + i*16 + c];
            }
            #pragma unroll
            for (int c = 0; c < 16; ++c) lds[KP_OFF + tid*16 + c] = acc[c];
        }
        // V row -> VP
        {
            const float4* p = (const float4*)(V + inoff + (size_t)tid * DM_);
            #pragma unroll
            for (int i = 0; i < 4; ++i) {
                float4 t = p[i];
                rowbuf[4*i+0] = t.x; rowbuf[4*i+1] = t.y;
                rowbuf[4*i+2] = t.z; rowbuf[4*i+3] = t.w;
            }
            #pragma unroll
            for (int c = 0; c < 16; ++c) acc[c] = 0.f;
            #pragma unroll
            for (int i = 0; i < 16; ++i) {
                const float vi = rowbuf[i];
                #pragma unroll
                for (int c = 0; c < 16; ++c) acc[c] += vi * lds[WV_OFF + i*16 + c];
            }
            #pragma unroll
            for (int c = 0; c < 16; ++c) lds[VP_OFF + tid*16 + c] = acc[c];
        }
    }
    __syncthreads();

    float emb[4][16];                     // all indices compile-time static below
    #pragma unroll
    for (int j = 0; j < 4; ++j)
        #pragma unroll
        for (int c = 0; c < 16; ++c) emb[j][c] = 0.f;

    const int z0 = w * 64;
    float* aout = attn_out + (size_t)bn * NL_ * NL_;

    // ---- main loop: 2 row-pair phases x 2 column-groups of 32 ----
    // Per phase only Qp[2][16] + atr[2][32] are register-hot; each attn row
    // segment is written as one 128-B contiguous burst = one full L2 line
    // from one lane -> single writeback, no partial-line refetch.
    #pragma unroll
    for (int p = 0; p < 2; ++p) {
        // rows for this pair: r0 = 128p + l, r1 = 128p + 64 + l
        float Qp[2][16];
        #pragma unroll
        for (int jj = 0; jj < 2; ++jj) {
            const int row = 128*p + 64*jj + l;   // stride-17: conflict-free
            #pragma unroll
            for (int c = 0; c < 16; ++c) Qp[jj][c] = lds[QP_OFF + row*17 + c];
        }

        #pragma unroll 1
        for (int g = 0; g < 2; ++g) {
            float atr[2][32];             // 128 B per row, fully static indices
            #pragma unroll
            for (int zz = 0; zz < 32; ++zz) {
                const int z = z0 + g*32 + zz;
                // broadcast reads (wave-uniform address: conflict-free)
                const float4 k0 = *(const float4*)&lds[KP_OFF + z*16 + 0];
                const float4 k1 = *(const float4*)&lds[KP_OFF + z*16 + 4];
                const float4 k2 = *(const float4*)&lds[KP_OFF + z*16 + 8];
                const float4 k3 = *(const float4*)&lds[KP_OFF + z*16 + 12];
                const float4 v0 = *(const float4*)&lds[VP_OFF + z*16 + 0];
                const float4 v1 = *(const float4*)&lds[VP_OFF + z*16 + 4];
                const float4 v2 = *(const float4*)&lds[VP_OFF + z*16 + 8];
                const float4 v3 = *(const float4*)&lds[VP_OFF + z*16 + 12];
                #pragma unroll
                for (int jj = 0; jj < 2; ++jj) {
                    float s0 = Qp[jj][0]*k0.x + Qp[jj][1]*k0.y + Qp[jj][2]*k0.z + Qp[jj][3]*k0.w
                             + Qp[jj][4]*k1.x + Qp[jj][5]*k1.y + Qp[jj][6]*k1.z + Qp[jj][7]*k1.w;
                    float s1 = Qp[jj][8]*k2.x + Qp[jj][9]*k2.y + Qp[jj][10]*k2.z + Qp[jj][11]*k2.w
                             + Qp[jj][12]*k3.x + Qp[jj][13]*k3.y + Qp[jj][14]*k3.z + Qp[jj][15]*k3.w;
                    s0 = fmaxf(s0, 0.f);
                    s1 = fmaxf(s1, 0.f);
                    atr[jj][zz] = 0.5f * (s0 + s1);
                    emb[2*p+jj][0]  += s0*v0.x; emb[2*p+jj][1]  += s0*v0.y;
                    emb[2*p+jj][2]  += s0*v0.z; emb[2*p+jj][3]  += s0*v0.w;
                    emb[2*p+jj][4]  += s0*v1.x; emb[2*p+jj][5]  += s0*v1.y;
                    emb[2*p+jj][6]  += s0*v1.z; emb[2*p+jj][7]  += s0*v1.w;
                    emb[2*p+jj][8]  += s1*v2.x; emb[2*p+jj][9]  += s1*v2.y;
                    emb[2*p+jj][10] += s1*v2.z; emb[2*p+jj][11] += s1*v2.w;
                    emb[2*p+jj][12] += s1*v3.x; emb[2*p+jj][13] += s1*v3.y;
                    emb[2*p+jj][14] += s1*v3.z; emb[2*p+jj][15] += s1*v3.w;
                }
            }
            // store: 128 B contiguous, 128-B aligned per row = one full L2 line
            #pragma unroll
            for (int jj = 0; jj < 2; ++jj) {
                float4* dst = (float4*)&aout[(size_t)(128*p + 64*jj + l) * NL_ + z0 + g*32];
                #pragma unroll
                for (int q = 0; q < 8; ++q)
                    dst[q] = make_float4(atr[jj][4*q+0], atr[jj][4*q+1],
                                         atr[jj][4*q+2], atr[jj][4*q+3]);
            }
        }
    }

    // ---- cross-wave emb reduction (z-split partials) ----
    __syncthreads();                      // QP/KP/VP dead from here
    if (w == 0) {
        #pragma unroll
        for (int j = 0; j < 4; ++j)
            #pragma unroll
            for (int c = 0; c < 16; ++c) lds[EMBA_OFF + (64*j+l)*17 + c] = emb[j][c];
    } else if (w == 1) {
        #pragma unroll
        for (int j = 0; j < 4; ++j)
            #pragma unroll
            for (int c = 0; c < 16; ++c) lds[EMBB_OFF + (64*j+l)*17 + c] = emb[j][c];
    }
    __syncthreads();
    if (w == 2) {
        #pragma unroll
        for (int j = 0; j < 4; ++j)
            #pragma unroll
            for (int c = 0; c < 16; ++c) lds[EMBA_OFF + (64*j+l)*17 + c] += emb[j][c];
    } else if (w == 3) {
        #pragma unroll
        for (int j = 0; j < 4; ++j)
            #pragma unroll
            for (int c = 0; c < 16; ++c) lds[EMBB_OFF + (64*j+l)*17 + c] += emb[j][c];
    }
    __syncthreads();

    // ---- output projection: thread t owns row t ----
    float e[16];
    #pragma unroll
    for (int c = 0; c < 16; ++c)
        e[c] = lds[EMBA_OFF + tid*17 + c] + lds[EMBB_OFF + tid*17 + c];

    float pr[16];
    #pragma unroll
    for (int o = 0; o < 16; ++o) pr[o] = 0.f;
    #pragma unroll
    for (int a = 0; a < 2; ++a) {
        #pragma unroll
        for (int m = 0; m < 8; ++m) {
            const float ev = e[a*8 + m];
            #pragma unroll
            for (int o = 0; o < 16; ++o) pr[o] += ev * lds[WO_OFF + m*32 + a*16 + o];
        }
    }
    float4* po = (float4*)(proj_out + (size_t)bn * NL_ * DOUT_ + (size_t)tid * DOUT_);
    po[0] = make_float4(pr[0],  pr[1],  pr[2],  pr[3]);
    po[1] = make_float4(pr[4],  pr[5],  pr[6],  pr[7]);
    po[2] = make_float4(pr[8],  pr[9],  pr[10], pr[11]);
    po[3] = make_float4(pr[12], pr[13], pr[14], pr[15]);
}

extern "C" void kernel_launch(void* const* d_in, const int* in_sizes, int n_in,
                              void* d_out, int out_size, void* d_ws, size_t ws_size,
                              hipStream_t stream) {
    const float* Q  = (const float*)d_in[0];
    const float* K  = (const float*)d_in[1];
    const float* V  = (const float*)d_in[2];
    const float* Wq = (const float*)d_in[3];
    const float* Wk = (const float*)d_in[4];
    const float* Wv = (const float*)d_in[5];
    const float* Wo = (const float*)d_in[6];

    float* proj = (float*)d_out;
    float* attn = (float*)d_out + PROJ_ELEMS;

    mha_relu_kernel<<<NBN, 256, 0, stream>>>(Q, K, V, Wq, Wk, Wv, Wo, proj, attn);
}

// Round 8
// 230.100 us; speedup vs baseline: 1.4273x; 1.4273x over previous
//
#include <hip/hip_runtime.h>

// Problem constants
#define B_    16
#define N1_   32
#define NL_   256
#define DM_   16
#define A_    2
#define DK_   8
#define DV_   8
#define DOUT_ 16

#define NBN   (B_ * N1_)                  // 512 blocks
#define PROJ_ELEMS (NBN * NL_ * DOUT_)    // 2097152

// LDS layout (float offsets). QP padded to stride 17 (conflict-free strided reads).
#define QP_OFF   0                        // 256*17 = 4352
#define KP_OFF   4352                     // 256*16 = 4096 (16B-aligned)
#define VP_OFF   8448                     // 4096
#define WQ_OFF   12544                    // 256
#define WK_OFF   12800                    // 256
#define WV_OFF   13056                    // 256
#define WO_OFF   13312                    // 256
#define LDS_FLOATS 13568                  // 54272 B -> 2 blocks/CU
// AT_T aliases the QP region once Qp is in registers: [32 cols][stride 129],
// 32*129 = 4128 <= 4352. Holds a 128-row x 32-col attn half-tile TRANSPOSED.
#define AT_OFF   0
#define ATS      129
// Epilogue aliases (QP/KP/VP dead by then; weights region untouched):
#define EMBA_OFF 0
#define EMBB_OFF 4352

__global__ __launch_bounds__(256, 2)
void mha_relu_kernel(const float* __restrict__ Q,
                     const float* __restrict__ K,
                     const float* __restrict__ V,
                     const float* __restrict__ Wq,
                     const float* __restrict__ Wk,
                     const float* __restrict__ Wv,
                     const float* __restrict__ Wo,
                     float* __restrict__ proj_out,
                     float* __restrict__ attn_out)
{
    __shared__ float lds[LDS_FLOATS];

    const int tid = threadIdx.x;
    const int bn  = blockIdx.x;
    const int w   = tid >> 6;             // wave id 0..3
    const int l   = tid & 63;             // lane; owns rows 64j+l, j=0..3

    // ---- weights -> LDS ----
    lds[WQ_OFF + tid] = Wq[tid];
    lds[WK_OFF + tid] = Wk[tid];
    lds[WV_OFF + tid] = Wv[tid];
    lds[WO_OFF + tid] = Wo[tid];
    __syncthreads();

    const size_t inoff = (size_t)bn * NL_ * DM_;

    // ---- phase 1: per-row projections (thread t computes row t) ----
    {
        float rowbuf[16], acc[16];

        // Q row -> QP (padded stride 17)
        {
            const float4* p = (const float4*)(Q + inoff + (size_t)tid * DM_);
            #pragma unroll
            for (int i = 0; i < 4; ++i) {
                float4 t = p[i];
                rowbuf[4*i+0] = t.x; rowbuf[4*i+1] = t.y;
                rowbuf[4*i+2] = t.z; rowbuf[4*i+3] = t.w;
            }
            #pragma unroll
            for (int c = 0; c < 16; ++c) acc[c] = 0.f;
            #pragma unroll
            for (int i = 0; i < 16; ++i) {
                const float qi = rowbuf[i];
                #pragma unroll
                for (int c = 0; c < 16; ++c) acc[c] += qi * lds[WQ_OFF + i*16 + c];
            }
            #pragma unroll
            for (int c = 0; c < 16; ++c) lds[QP_OFF + tid*17 + c] = acc[c];
        }
        // K row -> KP (stride 16)
        {
            const float4* p = (const float4*)(K + inoff + (size_t)tid * DM_);
            #pragma unroll
            for (int i = 0; i < 4; ++i) {
                float4 t = p[i];
                rowbuf[4*i+0] = t.x; rowbuf[4*i+1] = t.y;
                rowbuf[4*i+2] = t.z; rowbuf[4*i+3] = t.w;
            }
            #pragma unroll
            for (int c = 0; c < 16; ++c) acc[c] = 0.f;
            #pragma unroll
            for (int i = 0; i < 16; ++i) {
                const float ki = rowbuf[i];
                #pragma unroll
                for (int c = 0; c < 16; ++c) acc[c] += ki * lds[WK_OFF + i*16 + c];
            }
            #pragma unroll
            for (int c = 0; c < 16; ++c) lds[KP_OFF + tid*16 + c] = acc[c];
        }
        // V row -> VP
        {
            const float4* p = (const float4*)(V + inoff + (size_t)tid * DM_);
            #pragma unroll
            for (int i = 0; i < 4; ++i) {
                float4 t = p[i];
                rowbuf[4*i+0] = t.x; rowbuf[4*i+1] = t.y;
                rowbuf[4*i+2] = t.z; rowbuf[4*i+3] = t.w;
            }
            #pragma unroll
            for (int c = 0; c < 16; ++c) acc[c] = 0.f;
            #pragma unroll
            for (int i = 0; i < 16; ++i) {
                const float vi = rowbuf[i];
                #pragma unroll
                for (int c = 0; c < 16; ++c) acc[c] += vi * lds[WV_OFF + i*16 + c];
            }
            #pragma unroll
            for (int c = 0; c < 16; ++c) lds[VP_OFF + tid*16 + c] = acc[c];
        }
    }
    __syncthreads();

    // ---- this lane's 4 Qp rows -> registers (stride-17: 2-way, free) ----
    float Qp[4][16];
    #pragma unroll
    for (int j = 0; j < 4; ++j) {
        const int row = 64*j + l;
        #pragma unroll
        for (int c = 0; c < 16; ++c) Qp[j][c] = lds[QP_OFF + row*17 + c];
    }

    float emb[4][16];
    #pragma unroll
    for (int j = 0; j < 4; ++j)
        #pragma unroll
        for (int c = 0; c < 16; ++c) emb[j][c] = 0.f;

    float* aout = attn_out + (size_t)bn * NL_ * NL_;

    // ---- main loop: 8 col-tiles of 32. Wave w computes interleaved cols
    // z = 32t + 8w + e (e=0..7), so every tile has all 4 waves' output.
    // Stores go LDS-transposed so each global wave-instruction writes
    // 8 rows x 32 cols = full 128-B L2 lines (spatially coalesced).
    #pragma unroll 1
    for (int t = 0; t < 8; ++t) {
        float atr[4][8];
        #pragma unroll
        for (int e = 0; e < 8; ++e) {
            const int z = 32*t + 8*w + e;
            // broadcast reads (wave-uniform address: conflict-free)
            const float4 k0 = *(const float4*)&lds[KP_OFF + z*16 + 0];
            const float4 k1 = *(const float4*)&lds[KP_OFF + z*16 + 4];
            const float4 k2 = *(const float4*)&lds[KP_OFF + z*16 + 8];
            const float4 k3 = *(const float4*)&lds[KP_OFF + z*16 + 12];
            const float4 v0 = *(const float4*)&lds[VP_OFF + z*16 + 0];
            const float4 v1 = *(const float4*)&lds[VP_OFF + z*16 + 4];
            const float4 v2 = *(const float4*)&lds[VP_OFF + z*16 + 8];
            const float4 v3 = *(const float4*)&lds[VP_OFF + z*16 + 12];
            #pragma unroll
            for (int j = 0; j < 4; ++j) {
                float s0 = Qp[j][0]*k0.x + Qp[j][1]*k0.y + Qp[j][2]*k0.z + Qp[j][3]*k0.w
                         + Qp[j][4]*k1.x + Qp[j][5]*k1.y + Qp[j][6]*k1.z + Qp[j][7]*k1.w;
                float s1 = Qp[j][8]*k2.x + Qp[j][9]*k2.y + Qp[j][10]*k2.z + Qp[j][11]*k2.w
                         + Qp[j][12]*k3.x + Qp[j][13]*k3.y + Qp[j][14]*k3.z + Qp[j][15]*k3.w;
                s0 = fmaxf(s0, 0.f);
                s1 = fmaxf(s1, 0.f);
                atr[j][e] = 0.5f * (s0 + s1);
                emb[j][0]  += s0*v0.x; emb[j][1]  += s0*v0.y; emb[j][2]  += s0*v0.z; emb[j][3]  += s0*v0.w;
                emb[j][4]  += s0*v1.x; emb[j][5]  += s0*v1.y; emb[j][6]  += s0*v1.z; emb[j][7]  += s0*v1.w;
                emb[j][8]  += s1*v2.x; emb[j][9]  += s1*v2.y; emb[j][10] += s1*v2.z; emb[j][11] += s1*v2.w;
                emb[j][12] += s1*v3.x; emb[j][13] += s1*v3.y; emb[j][14] += s1*v3.z; emb[j][15] += s1*v3.w;
            }
        }

        // ---- two 128-row halves through the transposed AT tile ----
        #pragma unroll
        for (int h = 0; h < 2; ++h) {
            __syncthreads();              // AT free (prev reads done; 1st iter: Qp loads done)
            // write: lanes vary -> addr stride 1 -> bank permutation, free
            #pragma unroll
            for (int jj = 0; jj < 2; ++jj)
                #pragma unroll
                for (int e = 0; e < 8; ++e)
                    lds[AT_OFF + (8*w + e)*ATS + 64*jj + l] = atr[2*h + jj][e];
            __syncthreads();
            // cooperative store: one wave instr = 8 rows x 32 cols (full lines)
            #pragma unroll
            for (int i = 0; i < 4; ++i) {
                const int idx4 = i*256 + tid;     // float4 index in 128x32 half
                const int row  = idx4 >> 3;       // 0..127
                const int cg   = idx4 & 7;        // col-group (4 cols)
                const float4 vsto = make_float4(
                    lds[AT_OFF + (4*cg + 0)*ATS + row],
                    lds[AT_OFF + (4*cg + 1)*ATS + row],
                    lds[AT_OFF + (4*cg + 2)*ATS + row],
                    lds[AT_OFF + (4*cg + 3)*ATS + row]);
                *(float4*)&aout[(size_t)(h*128 + row) * NL_ + 32*t + 4*cg] = vsto;
            }
        }
    }

    // ---- cross-wave emb reduction (z-split partials) ----
    __syncthreads();                      // QP/KP/VP/AT dead from here
    if (w == 0) {
        #pragma unroll
        for (int j = 0; j < 4; ++j)
            #pragma unroll
            for (int c = 0; c < 16; ++c) lds[EMBA_OFF + (64*j+l)*17 + c] = emb[j][c];
    } else if (w == 1) {
        #pragma unroll
        for (int j = 0; j < 4; ++j)
            #pragma unroll
            for (int c = 0; c < 16; ++c) lds[EMBB_OFF + (64*j+l)*17 + c] = emb[j][c];
    }
    __syncthreads();
    if (w == 2) {
        #pragma unroll
        for (int j = 0; j < 4; ++j)
            #pragma unroll
            for (int c = 0; c < 16; ++c) lds[EMBA_OFF + (64*j+l)*17 + c] += emb[j][c];
    } else if (w == 3) {
        #pragma unroll
        for (int j = 0; j < 4; ++j)
            #pragma unroll
            for (int c = 0; c < 16; ++c) lds[EMBB_OFF + (64*j+l)*17 + c] += emb[j][c];
    }
    __syncthreads();

    // ---- output projection: thread t owns row t ----
    float e[16];
    #pragma unroll
    for (int c = 0; c < 16; ++c)
        e[c] = lds[EMBA_OFF + tid*17 + c] + lds[EMBB_OFF + tid*17 + c];

    float pr[16];
    #pragma unroll
    for (int o = 0; o < 16; ++o) pr[o] = 0.f;
    #pragma unroll
    for (int a = 0; a < 2; ++a) {
        #pragma unroll
        for (int m = 0; m < 8; ++m) {
            const float ev = e[a*8 + m];
            #pragma unroll
            for (int o = 0; o < 16; ++o) pr[o] += ev * lds[WO_OFF + m*32 + a*16 + o];
        }
    }
    float4* po = (float4*)(proj_out + (size_t)bn * NL_ * DOUT_ + (size_t)tid * DOUT_);
    po[0] = make_float4(pr[0],  pr[1],  pr[2],  pr[3]);
    po[1] = make_float4(pr[4],  pr[5],  pr[6],  pr[7]);
    po[2] = make_float4(pr[8],  pr[9],  pr[10], pr[11]);
    po[3] = make_float4(pr[12], pr[13], pr[14], pr[15]);
}

extern "C" void kernel_launch(void* const* d_in, const int* in_sizes, int n_in,
                              void* d_out, int out_size, void* d_ws, size_t ws_size,
                              hipStream_t stream) {
    const float* Q  = (const float*)d_in[0];
    const float* K  = (const float*)d_in[1];
    const float* V  = (const float*)d_in[2];
    const float* Wq = (const float*)d_in[3];
    const float* Wk = (const float*)d_in[4];
    const float* Wv = (const float*)d_in[5];
    const float* Wo = (const float*)d_in[6];

    float* proj = (float*)d_out;
    float* attn = (float*)d_out + PROJ_ELEMS;

    mha_relu_kernel<<<NBN, 256, 0, stream>>>(Q, K, V, Wq, Wk, Wv, Wo, proj, attn);
}

// Round 9
// 76.205 us; speedup vs baseline: 4.3098x; 3.0195x over previous
//
#include <hip/hip_runtime.h>

// Problem constants
#define B_    16
#define N1_   32
#define NL_   256
#define DM_   16
#define DOUT_ 16

#define NBN   (B_ * N1_)                  // 512 blocks
#define PROJ_ELEMS (NBN * NL_ * DOUT_)    // 2097152

// 512 threads = 8 waves. wave w: wr = w>>2 (row half), wz = w&3 (col slot).
// Lane owns rows 128*wr + {l, 64+l}; covers cols z = 32t + 8*wz + e (e=0..7).
// Live regs ~100: Qp[2][16] + emb[2][16] + atr[2][8] + float4 temps.
// LDS: sW* 4x256, sQP [256][17], sKP/sVP [256][16], sAT [256][33] = 86 KB.

__global__ __launch_bounds__(512, 2)
void mha_relu_kernel(const float* __restrict__ Q,
                     const float* __restrict__ K,
                     const float* __restrict__ V,
                     const float* __restrict__ Wq,
                     const float* __restrict__ Wk,
                     const float* __restrict__ Wv,
                     const float* __restrict__ Wo,
                     float* __restrict__ proj_out,
                     float* __restrict__ attn_out)
{
    __shared__ float sWq[256], sWk[256], sWv[256], sWo[256];
    __shared__ float sQP[256 * 17];       // stride 17 (conflict-free); aliased as
                                          // reduction bufs 2x[128][17] in epilogue
    __shared__ float sKP[256 * 16];
    __shared__ float sVP[256 * 16];
    __shared__ float sAT[256 * 33];       // attn staging tile, stride 33

    const int tid = threadIdx.x;          // 0..511
    const int bn  = blockIdx.x;
    const int w   = tid >> 6;             // wave 0..7
    const int l   = tid & 63;
    const int wr  = w >> 2;               // row half 0/1
    const int wz  = w & 3;                // col slot 0..3

    // ---- weights -> LDS ----
    if (tid < 256) { sWq[tid] = Wq[tid];       sWv[tid] = Wv[tid]; }
    else           { sWk[tid - 256] = Wk[tid - 256]; sWo[tid - 256] = Wo[tid - 256]; }
    __syncthreads();

    const size_t inoff = (size_t)bn * NL_ * DM_;

    // ---- projections: pass1 Q|K (512 threads), pass2 V (256 threads) ----
    {
        float rowbuf[16], acc[16];
        const int r = tid & 255;
        {
            const float* src  = (tid < 256) ? (Q + inoff + (size_t)r * DM_)
                                            : (K + inoff + (size_t)r * DM_);
            const float* wsrc = (tid < 256) ? sWq : sWk;
            const float4* p = (const float4*)src;
            #pragma unroll
            for (int i = 0; i < 4; ++i) {
                float4 t4 = p[i];
                rowbuf[4*i+0] = t4.x; rowbuf[4*i+1] = t4.y;
                rowbuf[4*i+2] = t4.z; rowbuf[4*i+3] = t4.w;
            }
            #pragma unroll
            for (int c = 0; c < 16; ++c) acc[c] = 0.f;
            #pragma unroll
            for (int i = 0; i < 16; ++i) {
                const float xi = rowbuf[i];
                #pragma unroll
                for (int c = 0; c < 16; ++c) acc[c] += xi * wsrc[i*16 + c];
            }
            if (tid < 256) {
                #pragma unroll
                for (int c = 0; c < 16; ++c) sQP[r*17 + c] = acc[c];
            } else {
                #pragma unroll
                for (int c = 0; c < 16; ++c) sKP[r*16 + c] = acc[c];
            }
        }
        if (tid < 256) {
            const float4* p = (const float4*)(V + inoff + (size_t)r * DM_);
            #pragma unroll
            for (int i = 0; i < 4; ++i) {
                float4 t4 = p[i];
                rowbuf[4*i+0] = t4.x; rowbuf[4*i+1] = t4.y;
                rowbuf[4*i+2] = t4.z; rowbuf[4*i+3] = t4.w;
            }
            #pragma unroll
            for (int c = 0; c < 16; ++c) acc[c] = 0.f;
            #pragma unroll
            for (int i = 0; i < 16; ++i) {
                const float vi = rowbuf[i];
                #pragma unroll
                for (int c = 0; c < 16; ++c) acc[c] += vi * sWv[i*16 + c];
            }
            #pragma unroll
            for (int c = 0; c < 16; ++c) sVP[r*16 + c] = acc[c];
        }
    }
    __syncthreads();

    // ---- this lane's 2 Qp rows -> registers (stride-17: conflict-free) ----
    float Qp[2][16];
    #pragma unroll
    for (int jj = 0; jj < 2; ++jj) {
        const int row = 128*wr + 64*jj + l;
        #pragma unroll
        for (int c = 0; c < 16; ++c) Qp[jj][c] = sQP[row*17 + c];
    }

    float emb[2][16];
    #pragma unroll
    for (int jj = 0; jj < 2; ++jj)
        #pragma unroll
        for (int c = 0; c < 16; ++c) emb[jj][c] = 0.f;

    float* aout = attn_out + (size_t)bn * NL_ * NL_;

    // ---- main loop: 8 col-tiles of 32; wave w owns cols 8wz..8wz+8 of each ----
    #pragma unroll 1
    for (int t = 0; t < 8; ++t) {
        float atr[2][8];
        #pragma unroll
        for (int e = 0; e < 8; ++e) {
            const int z = 32*t + 8*wz + e;
            float s0a = 0.f, s0b = 0.f, s1a = 0.f, s1b = 0.f; // [jj][head]
            {
                const float4* kp = (const float4*)&sKP[z*16];
                float4 x;
                x = kp[0];
                s0a += Qp[0][0]*x.x + Qp[0][1]*x.y + Qp[0][2]*x.z + Qp[0][3]*x.w;
                s1a += Qp[1][0]*x.x + Qp[1][1]*x.y + Qp[1][2]*x.z + Qp[1][3]*x.w;
                x = kp[1];
                s0a += Qp[0][4]*x.x + Qp[0][5]*x.y + Qp[0][6]*x.z + Qp[0][7]*x.w;
                s1a += Qp[1][4]*x.x + Qp[1][5]*x.y + Qp[1][6]*x.z + Qp[1][7]*x.w;
                x = kp[2];
                s0b += Qp[0][8]*x.x + Qp[0][9]*x.y + Qp[0][10]*x.z + Qp[0][11]*x.w;
                s1b += Qp[1][8]*x.x + Qp[1][9]*x.y + Qp[1][10]*x.z + Qp[1][11]*x.w;
                x = kp[3];
                s0b += Qp[0][12]*x.x + Qp[0][13]*x.y + Qp[0][14]*x.z + Qp[0][15]*x.w;
                s1b += Qp[1][12]*x.x + Qp[1][13]*x.y + Qp[1][14]*x.z + Qp[1][15]*x.w;
            }
            s0a = fmaxf(s0a, 0.f); s0b = fmaxf(s0b, 0.f);
            s1a = fmaxf(s1a, 0.f); s1b = fmaxf(s1b, 0.f);
            atr[0][e] = 0.5f * (s0a + s0b);
            atr[1][e] = 0.5f * (s1a + s1b);
            {
                const float4* vp = (const float4*)&sVP[z*16];
                float4 x;
                x = vp[0];
                emb[0][0]  += s0a*x.x; emb[0][1]  += s0a*x.y; emb[0][2]  += s0a*x.z; emb[0][3]  += s0a*x.w;
                emb[1][0]  += s1a*x.x; emb[1][1]  += s1a*x.y; emb[1][2]  += s1a*x.z; emb[1][3]  += s1a*x.w;
                x = vp[1];
                emb[0][4]  += s0a*x.x; emb[0][5]  += s0a*x.y; emb[0][6]  += s0a*x.z; emb[0][7]  += s0a*x.w;
                emb[1][4]  += s1a*x.x; emb[1][5]  += s1a*x.y; emb[1][6]  += s1a*x.z; emb[1][7]  += s1a*x.w;
                x = vp[2];
                emb[0][8]  += s0b*x.x; emb[0][9]  += s0b*x.y; emb[0][10] += s0b*x.z; emb[0][11] += s0b*x.w;
                emb[1][8]  += s1b*x.x; emb[1][9]  += s1b*x.y; emb[1][10] += s1b*x.z; emb[1][11] += s1b*x.w;
                x = vp[3];
                emb[0][12] += s0b*x.x; emb[0][13] += s0b*x.y; emb[0][14] += s0b*x.z; emb[0][15] += s0b*x.w;
                emb[1][12] += s1b*x.x; emb[1][13] += s1b*x.y; emb[1][14] += s1b*x.z; emb[1][15] += s1b*x.w;
            }
        }
        __syncthreads();                  // prev tile's AT reads complete
        #pragma unroll
        for (int jj = 0; jj < 2; ++jj)
            #pragma unroll
            for (int e = 0; e < 8; ++e)
                sAT[(128*wr + 64*jj + l)*33 + 8*wz + e] = atr[jj][e];
        __syncthreads();
        // cooperative store, round-2 proven shape: per wave-instr 2 rows x
        // 32 lanes x 4 B = two full 128-B aligned chunks
        #pragma unroll
        for (int i = 0; i < 16; ++i) {
            const int idx = i*512 + tid;  // 0..8191 over [256 rows][32 cols]
            const int row = idx >> 5;
            const int col = idx & 31;
            aout[(size_t)row * NL_ + 32*t + col] = sAT[row*33 + col];
        }
    }

    // ---- emb reduction: 4 col-slot partials per row-half, in dead sQP ----
    // red buf layout: half h at offset h*2176, [128][17]
    __syncthreads();
    if (wz == 0) {
        #pragma unroll
        for (int jj = 0; jj < 2; ++jj)
            #pragma unroll
            for (int c = 0; c < 16; ++c)
                sQP[wr*2176 + (64*jj + l)*17 + c] = emb[jj][c];
    }
    __syncthreads();
    if (wz == 1) {
        #pragma unroll
        for (int jj = 0; jj < 2; ++jj)
            #pragma unroll
            for (int c = 0; c < 16; ++c)
                sQP[wr*2176 + (64*jj + l)*17 + c] += emb[jj][c];
    }
    __syncthreads();
    if (wz == 2) {
        #pragma unroll
        for (int jj = 0; jj < 2; ++jj)
            #pragma unroll
            for (int c = 0; c < 16; ++c)
                sQP[wr*2176 + (64*jj + l)*17 + c] += emb[jj][c];
    }
    __syncthreads();
    if (wz == 3) {
        #pragma unroll
        for (int jj = 0; jj < 2; ++jj)
            #pragma unroll
            for (int c = 0; c < 16; ++c)
                sQP[wr*2176 + (64*jj + l)*17 + c] += emb[jj][c];
    }
    __syncthreads();

    // ---- output projection: threads 0..255, thread t owns row t ----
    if (tid < 256) {
        const int half = tid >> 7;
        const int r    = tid & 127;
        float e[16];
        #pragma unroll
        for (int c = 0; c < 16; ++c) e[c] = sQP[half*2176 + r*17 + c];

        float pr[16];
        #pragma unroll
        for (int o = 0; o < 16; ++o) pr[o] = 0.f;
        #pragma unroll
        for (int a = 0; a < 2; ++a) {
            #pragma unroll
            for (int m = 0; m < 8; ++m) {
                const float ev = e[a*8 + m];
                #pragma unroll
                for (int o = 0; o < 16; ++o) pr[o] += ev * sWo[m*32 + a*16 + o];
            }
        }
        float4* po = (float4*)(proj_out + (size_t)bn * NL_ * DOUT_ + (size_t)tid * DOUT_);
        po[0] = make_float4(pr[0],  pr[1],  pr[2],  pr[3]);
        po[1] = make_float4(pr[4],  pr[5],  pr[6],  pr[7]);
        po[2] = make_float4(pr[8],  pr[9],  pr[10], pr[11]);
        po[3] = make_float4(pr[12], pr[13], pr[14], pr[15]);
    }
}

extern "C" void kernel_launch(void* const* d_in, const int* in_sizes, int n_in,
                              void* d_out, int out_size, void* d_ws, size_t ws_size,
                              hipStream_t stream) {
    const float* Q  = (const float*)d_in[0];
    const float* K  = (const float*)d_in[1];
    const float* V  = (const float*)d_in[2];
    const float* Wq = (const float*)d_in[3];
    const float* Wk = (const float*)d_in[4];
    const float* Wv = (const float*)d_in[5];
    const float* Wo = (const float*)d_in[6];

    float* proj = (float*)d_out;
    float* attn = (float*)d_out + PROJ_ELEMS;

    mha_relu_kernel<<<NBN, 512, 0, stream>>>(Q, K, V, Wq, Wk, Wv, Wo, proj, attn);
}